// Round 4
// baseline (345.135 us; speedup 1.0000x reference)
//
#include <hip/hip_runtime.h>
#include <stdint.h>

// KMeans top-2 gap: N=1M x D=64, K=128, fp32.
// R4: fully-coalesced x loads (lane-contiguous dwordx4, 4x1KB dense per group)
// + wave-private padded-LDS transpose to MFMA fragment layout (no barrier;
// row stride 272B balances banks for both write and fragment read).
// Centroid fragments pre-scaled by -2 (exact) => epilogue d = acc + csq.

#define DD 64
#define KK 128

typedef __attribute__((ext_vector_type(8))) short bf16x8;
typedef __attribute__((ext_vector_type(4))) float f32x4;
typedef __attribute__((ext_vector_type(4))) unsigned int u32x4;

__device__ __forceinline__ uint32_t pk_bf16(float a, float b) {
  uint32_t ua = __builtin_bit_cast(uint32_t, a);
  uint32_t ub = __builtin_bit_cast(uint32_t, b);
  ua += 0x7fffu + ((ua >> 16) & 1u);   // RNE
  ub += 0x7fffu + ((ub >> 16) & 1u);
  return (ua >> 16) | (ub & 0xffff0000u);
}

__global__ __launch_bounds__(256, 3) void kmeans_top2_kernel(
    const float* __restrict__ x, const float* __restrict__ cent,
    float* __restrict__ out, int N, int ngroups) {
  // (-2*centroid) bf16 fragments, slot th = t*2+h: lane l holds
  // -2*cent[(l&15)+16t][(l>>4)*8+j+32h] -> A operand of mfma_16x16x32_bf16.
  __shared__ uint32_t fragA[16 * 64 * 4];        // 16 KB
  __shared__ float csq_lds[KK];
  __shared__ float4 stage[4][16 * 17];           // per-wave x-tile, row stride 17 float4

  const int tid = threadIdx.x;

  // ---- phase 1: centroids -> (-2c) bf16 fragments + fp32 sq-norms ----
  #pragma unroll
  for (int i = 0; i < 4; ++i) {
    int s = tid + i * 256;
    int l = s & 63;
    int th = s >> 6;
    int t = th >> 1, h = th & 1;
    int c = (l & 15) + 16 * t;
    int kb = ((l >> 4) << 3) + 32 * h;
    const float4* p = (const float4*)(cent + c * DD + kb);
    float4 f0 = p[0];
    float4 f1 = p[1];
    uint32_t* dst = &fragA[s * 4];
    dst[0] = pk_bf16(-2.f * f0.x, -2.f * f0.y);
    dst[1] = pk_bf16(-2.f * f0.z, -2.f * f0.w);
    dst[2] = pk_bf16(-2.f * f1.x, -2.f * f1.y);
    dst[3] = pk_bf16(-2.f * f1.z, -2.f * f1.w);
  }
  if (tid < KK) {
    const float4* p = (const float4*)(cent + tid * DD);
    float s = 0.f;
    #pragma unroll
    for (int i = 0; i < 16; ++i) {
      float4 f = p[i];
      s = fmaf(f.x, f.x, s);
      s = fmaf(f.y, f.y, s);
      s = fmaf(f.z, f.z, s);
      s = fmaf(f.w, f.w, s);
    }
    csq_lds[tid] = s;
  }
  __syncthreads();

  const int lane = tid & 63;
  const int q = lane >> 4;
  const int li = lane & 15;
  const int wv = tid >> 6;
  const int gwave = blockIdx.x * 4 + wv;
  const int nwaves = gridDim.x * 4;

  bf16x8 cfr[16];
  #pragma unroll
  for (int th = 0; th < 16; ++th)
    cfr[th] = *(const bf16x8*)&fragA[(th * 64 + lane) * 4];
  f32x4 cs[8];   // csq for c = 16t + q*4 + r
  #pragma unroll
  for (int t = 0; t < 8; ++t)
    cs[t] = *(const f32x4*)&csq_lds[16 * t + q * 4];

  float4* stv = stage[wv];
  const float4* xv = (const float4*)x;
  const int idxmax = N * 16 - 1;   // total float4 count - 1 (16M-1 fits int)

  for (int g = gwave; g < ngroups; g += nwaves) {
    // ---- coalesced 4KB load: lane l gets float4s g*256 + l + 64i ----
    int b = g * 256 + lane;
    float4 v0 = xv[min(b, idxmax)];
    float4 v1 = xv[min(b + 64, idxmax)];
    float4 v2 = xv[min(b + 128, idxmax)];
    float4 v3 = xv[min(b + 192, idxmax)];

    // ---- scatter to wave-private padded LDS (row r at r*17 float4s) ----
    // instr i holds row 4i+q, 16B-chunk li
    stv[(q + 0) * 17 + li] = v0;
    stv[(q + 4) * 17 + li] = v1;
    stv[(q + 8) * 17 + li] = v2;
    stv[(q + 12) * 17 + li] = v3;

    // ---- fragment read: row li, chunks 2q,2q+1 (k 0..31) & +8 (k 32..63) ----
    float4 f0 = stv[li * 17 + 2 * q];
    float4 f1 = stv[li * 17 + 2 * q + 1];
    float4 f2 = stv[li * 17 + 8 + 2 * q];
    float4 f3 = stv[li * 17 + 9 + 2 * q];

    u32x4 ua, ub;
    ua.x = pk_bf16(f0.x, f0.y);
    ua.y = pk_bf16(f0.z, f0.w);
    ua.z = pk_bf16(f1.x, f1.y);
    ua.w = pk_bf16(f1.z, f1.w);
    ub.x = pk_bf16(f2.x, f2.y);
    ub.y = pk_bf16(f2.z, f2.w);
    ub.z = pk_bf16(f3.x, f3.y);
    ub.w = pk_bf16(f3.z, f3.w);
    bf16x8 P0 = __builtin_bit_cast(bf16x8, ua);
    bf16x8 P1 = __builtin_bit_cast(bf16x8, ub);

    f32x4 acc[8];
    #pragma unroll
    for (int t = 0; t < 8; ++t) acc[t] = (f32x4){0.f, 0.f, 0.f, 0.f};
    #pragma unroll
    for (int t = 0; t < 8; ++t) {
      acc[t] = __builtin_amdgcn_mfma_f32_16x16x32_bf16(cfr[2 * t], P0, acc[t], 0, 0, 0);
      acc[t] = __builtin_amdgcn_mfma_f32_16x16x32_bf16(cfr[2 * t + 1], P1, acc[t], 0, 0, 0);
    }

    // ---- lane owns point li: d = acc + csq; top-2 via two chains + merge ----
    float a1 = 3.4e38f, a2 = 3.4e38f, b1 = 3.4e38f, b2 = 3.4e38f;
    #pragma unroll
    for (int t = 0; t < 4; ++t) {
      #pragma unroll
      for (int r = 0; r < 4; ++r) {
        float da = acc[t][r] + cs[t][r];
        a2 = __builtin_amdgcn_fmed3f(a1, a2, da);
        a1 = fminf(a1, da);
        float db = acc[t + 4][r] + cs[t + 4][r];
        b2 = __builtin_amdgcn_fmed3f(b1, b2, db);
        b1 = fminf(b1, db);
      }
    }
    float m1 = fminf(a1, b1);
    float m2 = fminf(fminf(a2, b2), fmaxf(a1, b1));
    // merge across q (lanes l, l^16, l^32, l^48 share point li)
    #pragma unroll
    for (int m = 16; m <= 32; m <<= 1) {
      float o1 = __shfl_xor(m1, m, 64);
      float o2 = __shfl_xor(m2, m, 64);
      float hi = fmaxf(m1, o1);
      m1 = fminf(m1, o1);
      m2 = fminf(fminf(m2, o2), hi);
    }

    if (q == 0) {
      int prow = g * 16 + li;
      if (prow < N) out[prow] = m2 - m1;
    }
  }
}

extern "C" void kernel_launch(void* const* d_in, const int* in_sizes, int n_in,
                              void* d_out, int out_size, void* d_ws, size_t ws_size,
                              hipStream_t stream) {
  const float* x = (const float*)d_in[0];
  const float* cent = (const float*)d_in[1];
  float* out = (float*)d_out;
  int N = in_sizes[0] / DD;
  int ngroups = (N + 15) / 16;   // 62500
  kmeans_top2_kernel<<<dim3(2048), dim3(256), 0, stream>>>(x, cent, out, N, ngroups);
}